// Round 8
// baseline (500.427 us; speedup 1.0000x reference)
//
#include <hip/hip_runtime.h>

#define M_DIM 256
#define N_DIM 8192
#define K_DIM 8192
#define KSPLIT 4
#define KLEN (K_DIM / KSPLIT)   // 2048
#define NC (KLEN / 128)         // 16 chunks of 128 k
#define CHE 32768               // x-chunk elements (256 rows x 128 k)
#define CHB 65536               // x-chunk bytes (f16)

typedef _Float16 half_t;
typedef __attribute__((ext_vector_type(8))) _Float16 half8;
typedef __attribute__((ext_vector_type(4))) float f32x4;
typedef __attribute__((ext_vector_type(4))) unsigned int u32x4;

__device__ __forceinline__ unsigned int pk2(float a, float b) {
  // v_cvt_pkrtz: exact for integers |v| <= 2048 (W); x pre-rounded RNE in convert_x
  return __builtin_bit_cast(unsigned int, __builtin_amdgcn_cvt_pkrtz(a, b));
}
__device__ __forceinline__ void gl16(const void* g, void* l) {
  __builtin_amdgcn_global_load_lds(
      (const __attribute__((address_space(1))) unsigned int*)g,
      (__attribute__((address_space(3))) unsigned int*)l, 16, 0, 0);
}

// ---- x f32 [256][8192] -> f16, chunk-tiled [kc][row][128], 16B-chunk XOR swizzle
// (swizzle baked into SOURCE: linear global_load_lds dest + XOR'd ds_read agree)
__global__ __launch_bounds__(256) void convert_x(const float* __restrict__ x,
                                                 half_t* __restrict__ xh) {
  const int gid = blockIdx.x * 256 + threadIdx.x;  // 262144 threads x 8 elems
  const int row = gid >> 10;
  const int k0 = (gid & 1023) << 3;
  float4 v0 = *(const float4*)(x + (size_t)row * K_DIM + k0);
  float4 v1 = *(const float4*)(x + (size_t)row * K_DIM + k0 + 4);
  half8 h;
  h[0] = (half_t)v0.x; h[1] = (half_t)v0.y; h[2] = (half_t)v0.z; h[3] = (half_t)v0.w;
  h[4] = (half_t)v1.x; h[5] = (half_t)v1.y; h[6] = (half_t)v1.z; h[7] = (half_t)v1.w;
  const int kc = k0 >> 7;                 // global 128-k chunk
  const int c16 = (k0 >> 3) & 15;         // 16B slot within chunk row
  *(half8*)(xh + (size_t)kc * CHE + row * 128 + ((c16 ^ (row & 7)) << 3)) = h;
}

// out[m][n] += scale * sum_k x[m][k] * W[n][k]   (+bias on ks==0)
// A-operand = W (wave-private, global->reg->f16, distance-2-chunk prefetch)
// B-operand = x (static per-chunk in LDS, double-buffered)
__global__ __launch_bounds__(512, 2) void qgemm(
    const half_t* __restrict__ xh, const int* __restrict__ Wq,
    const float* __restrict__ scales, const float* __restrict__ bias,
    float* __restrict__ out) {
  __shared__ __align__(1024) char lds[2 * CHB];  // 128 KB -> 1 block/CU

  const int tid = threadIdx.x;
  const int bid = blockIdx.x;
  const int p = bid & 7;              // XCD (round-robin dispatch)
  const int ks = p >> 1;              // k-quarter: its 1MB x-slice lives in 2 XCDs' L2
  const int t = ((bid >> 3) << 1) | (p & 1);  // N-tile 0..63
  const int col0 = t * 128;

  const int wid = tid >> 6, lane = tid & 63;
  const int r16 = lane & 15, g4 = lane >> 4;
  const int n0 = col0 + wid * 16;     // wave's private 16 W-rows

  // W: lane supplies A-frag row r16, k-group g4 (8 consecutive ints = 2 dwordx4)
  const int* wp = Wq + (size_t)(n0 + r16) * K_DIM + ks * KLEN + g4 * 8;
  // x chunks for this k-quarter
  const half_t* xbase = xh + (size_t)(ks * NC) * CHE;

  // per-k-step ds_read base (XOR swizzle -> 2 lanes/slot, conflict-free)
  int rb[4];
#pragma unroll
  for (int ks4 = 0; ks4 < 4; ++ks4)
    rb[ks4] = r16 * 256 + ((((ks4 << 2) + g4) ^ (r16 & 7)) << 4);

  f32x4 acc[16];
#pragma unroll
  for (int i = 0; i < 16; ++i) acc[i] = (f32x4){0.f, 0.f, 0.f, 0.f};

  int4 sA[8], sB[8];  // W double-set: 32 ints/lane per chunk (statically indexed)

  // ---- prologue: [x(0) gl16 x8][W(0) x8 -> sA][W(1) x8 -> sB]; drain x0+W0 ----
#pragma unroll
  for (int i = 0; i < 8; ++i)
    gl16(xbase + (tid + i * 512) * 8, lds + (tid + i * 512) * 16);
  __builtin_amdgcn_sched_barrier(0);
#pragma unroll
  for (int ks4 = 0; ks4 < 4; ++ks4) {
    sA[2 * ks4] = *(const int4*)(wp + ks4 * 32);
    sA[2 * ks4 + 1] = *(const int4*)(wp + ks4 * 32 + 4);
  }
#pragma unroll
  for (int ks4 = 0; ks4 < 4; ++ks4) {
    sB[2 * ks4] = *(const int4*)(wp + 128 + ks4 * 32);
    sB[2 * ks4 + 1] = *(const int4*)(wp + 128 + ks4 * 32 + 4);
  }
  __builtin_amdgcn_sched_barrier(0);
  asm volatile("s_waitcnt vmcnt(8)" ::: "memory");  // x0+W0 done; W1 in flight
  __builtin_amdgcn_s_barrier();

  // chunk C: stage x(C+1); per k-step {cvt W(C), reload set with W(C+2), 16 MFMA};
  // end: vmcnt(8) (drains W(C+1)+x(C+1), leaves W(C+2)) + barrier.
#define CHUNK(C, SET, STAGE, PREF)                                            \
  {                                                                           \
    const char* bufc = lds + ((C) & 1) * CHB;                                 \
    if (STAGE) {                                                              \
      char* bn = lds + (((C) + 1) & 1) * CHB;                                 \
      const half_t* src = xbase + (size_t)((C) + 1) * CHE;                    \
      _Pragma("unroll") for (int i = 0; i < 8; ++i)                           \
          gl16(src + (tid + i * 512) * 8, bn + (tid + i * 512) * 16);         \
    }                                                                         \
    __builtin_amdgcn_sched_barrier(0);                                        \
    _Pragma("unroll") for (int ks4 = 0; ks4 < 4; ++ks4) {                     \
      int4 w0 = SET[2 * ks4], w1 = SET[2 * ks4 + 1];                          \
      if (PREF) { /* WAR-safe: cvt reads issue before reload writes back */   \
        const int* q = wp + ((C) + 2) * 128 + ks4 * 32;                       \
        SET[2 * ks4] = *(const int4*)q;                                       \
        SET[2 * ks4 + 1] = *(const int4*)(q + 4);                             \
      }                                                                       \
      u32x4 au;                                                               \
      au.x = pk2((float)w0.x, (float)w0.y);                                   \
      au.y = pk2((float)w0.z, (float)w0.w);                                   \
      au.z = pk2((float)w1.x, (float)w1.y);                                   \
      au.w = pk2((float)w1.z, (float)w1.w);                                   \
      half8 af = __builtin_bit_cast(half8, au);                               \
      _Pragma("unroll") for (int mt = 0; mt < 16; ++mt) {                     \
        half8 bf = *(const half8*)(bufc + mt * 4096 + rb[ks4]);               \
        acc[mt] = __builtin_amdgcn_mfma_f32_16x16x32_f16(af, bf, acc[mt], 0, 0, 0); \
      }                                                                       \
    }                                                                         \
    __builtin_amdgcn_sched_barrier(0);                                        \
  }

  for (int pr = 0; pr < 7; ++pr) {  // chunks 0..13
    CHUNK(2 * pr, sA, 1, 1)
    asm volatile("s_waitcnt vmcnt(8)" ::: "memory");
    __builtin_amdgcn_s_barrier();
    CHUNK(2 * pr + 1, sB, 1, 1)
    asm volatile("s_waitcnt vmcnt(8)" ::: "memory");
    __builtin_amdgcn_s_barrier();
  }
  CHUNK(14, sA, 1, 0)  // stages x(15); no W(16)
  asm volatile("s_waitcnt vmcnt(0)" ::: "memory");
  __builtin_amdgcn_s_barrier();
  CHUNK(15, sB, 0, 0)  // final: no stage, no prefetch, no wait
#undef CHUNK

  // ---- epilogue: D[n=(g4*4+j)][m=(mt*16+r16)] -> out[m][n], atomic k-split ----
  const float scale = scales[0];
  float4 bv4 = {0.f, 0.f, 0.f, 0.f};
  if (ks == 0) bv4 = *(const float4*)(bias + n0 + g4 * 4);
#pragma unroll
  for (int mt = 0; mt < 16; ++mt) {
    const int m = mt * 16 + r16;
    float* orow = out + (size_t)m * N_DIM + n0 + g4 * 4;
    atomicAdd(orow + 0, scale * acc[mt][0] + bv4.x);
    atomicAdd(orow + 1, scale * acc[mt][1] + bv4.y);
    atomicAdd(orow + 2, scale * acc[mt][2] + bv4.z);
    atomicAdd(orow + 3, scale * acc[mt][3] + bv4.w);
  }
}

extern "C" void kernel_launch(void* const* d_in, const int* in_sizes, int n_in,
                              void* d_out, int out_size, void* d_ws, size_t ws_size,
                              hipStream_t stream) {
  const float* x = (const float*)d_in[0];
  const int* Wq = (const int*)d_in[1];  // int8 weights widened to int32
  const float* scales = (const float*)d_in[2];
  const float* bias = (const float*)d_in[3];
  float* out = (float*)d_out;
  half_t* xh = (half_t*)d_ws;  // 4 MB chunk-tiled f16 x

  hipMemsetAsync(d_out, 0, (size_t)M_DIM * N_DIM * sizeof(float), stream);
  convert_x<<<dim3(1024), dim3(256), 0, stream>>>(x, xh);
  qgemm<<<dim3(256), dim3(512), 0, stream>>>(xh, Wq, scales, bias, out);
}